// Round 13
// baseline (571.930 us; speedup 1.0000x reference)
//
#include <hip/hip_runtime.h>

#define NN    100000
#define NE    640000
#define DIM   128
#define NPT   32    // nodes per fused tile
#define PAD   4     // LDS row pad: stride 528 B, 16B-aligned
#define WCH   16    // W chunk width -> Ws 8.4 KB; total LDS ~25.5 KB, 6 blk/CU
#define TILE  1024  // scan tile (elements per block)
#define NBLK  98    // ceil(NN / TILE)
#define CASTB 6250  // NN*DIM/8/256 (exact)
#define HISTB 2500  // NE/256 (exact)

typedef unsigned short ushortT;
typedef ushortT ushort8 __attribute__((ext_vector_type(8)));

__device__ __forceinline__ ushortT f2b(float f) {      // fp32 -> bf16 RNE
    unsigned b = __float_as_uint(f);
    return (ushortT)((b + 0x7FFFu + ((b >> 16) & 1u)) >> 16);
}
__device__ __forceinline__ float b2f(ushortT u) {      // bf16 -> fp32 exact
    return __uint_as_float(((unsigned)u) << 16);
}

// ws layout (4-byte units):
//   cnts [0, NN)  offs [NN, 2NN+4)  curs [2NN+4, 3NN+4)
//   esrc [3NN+4, +NE)  blksum [+128]  x_bf16 [..., +NN*DIM*2 B]  ~29.4 MB

// ---------------------------------------------------------------------------
// 0) prep: blocks [0,CASTB) cast x->bf16; blocks [CASTB,CASTB+HISTB) hist.
//    cnts zeroed beforehand by hipMemsetAsync.
// ---------------------------------------------------------------------------
__global__ __launch_bounds__(256) void prep_k(
    const float* __restrict__ x, ushortT* __restrict__ xb,
    const int* __restrict__ ei, unsigned* __restrict__ cnts)
{
    int bid = blockIdx.x;
    if (bid < CASTB) {
        int i = (bid * 256 + threadIdx.x) * 8;
        float4 f0 = *reinterpret_cast<const float4*>(x + i);
        float4 f1 = *reinterpret_cast<const float4*>(x + i + 4);
        ushort8 u;
        u[0] = f2b(f0.x); u[1] = f2b(f0.y); u[2] = f2b(f0.z); u[3] = f2b(f0.w);
        u[4] = f2b(f1.x); u[5] = f2b(f1.y); u[6] = f2b(f1.z); u[7] = f2b(f1.w);
        *reinterpret_cast<ushort8*>(xb + i) = u;
    } else {
        int e = (bid - CASTB) * 256 + threadIdx.x;
        int t = ei[NE + e];
        if ((unsigned)t < NN) atomicAdd(&cnts[t], 1u);
    }
}

// ---------------------------------------------------------------------------
// 2a) Per-block sums of 1024-elem tiles.
// ---------------------------------------------------------------------------
__global__ __launch_bounds__(256) void scan_a_k(
    const unsigned* __restrict__ cnts, unsigned* __restrict__ blksum)
{
    __shared__ unsigned red[4];
    int t    = threadIdx.x;
    int base = blockIdx.x * TILE + t * 4;
    unsigned v = 0;
    if (base + 3 < NN) {
        uint4 u = *reinterpret_cast<const uint4*>(cnts + base);
        v = u.x + u.y + u.z + u.w;
    } else {
        for (int k = 0; k < 4; ++k) if (base + k < NN) v += cnts[base + k];
    }
    #pragma unroll
    for (int off = 32; off; off >>= 1) v += __shfl_down(v, off);
    if ((t & 63) == 0) red[t >> 6] = v;
    __syncthreads();
    if (t == 0) blksum[blockIdx.x] = red[0] + red[1] + red[2] + red[3];
}

// ---------------------------------------------------------------------------
// 2b) Per-block scan (+ inline base from blksum) -> offs, curs.
// ---------------------------------------------------------------------------
__global__ __launch_bounds__(256) void scan_c_k(
    const unsigned* __restrict__ cnts,
    const unsigned* __restrict__ blksum,
    unsigned* __restrict__ offs,
    unsigned* __restrict__ curs)
{
    __shared__ unsigned ps[256];
    __shared__ unsigned lsum[4];
    int t    = threadIdx.x;
    int bid  = blockIdx.x;
    int base = bid * TILE + t * 4;

    unsigned part = 0;
    for (int j = t; j < bid; j += 256) part += blksum[j];
    #pragma unroll
    for (int off = 32; off; off >>= 1) part += __shfl_down(part, off);
    if ((t & 63) == 0) lsum[t >> 6] = part;

    unsigned v0 = 0, v1 = 0, v2 = 0, v3 = 0;
    if (base + 3 < NN) {
        uint4 u = *reinterpret_cast<const uint4*>(cnts + base);
        v0 = u.x; v1 = u.y; v2 = u.z; v3 = u.w;
    } else {
        if (base     < NN) v0 = cnts[base];
        if (base + 1 < NN) v1 = cnts[base + 1];
        if (base + 2 < NN) v2 = cnts[base + 2];
    }
    ps[t] = v0 + v1 + v2 + v3;
    __syncthreads();
    for (int off = 1; off < 256; off <<= 1) {
        unsigned u = (t >= off) ? ps[t - off] : 0u;
        __syncthreads();
        ps[t] += u;
        __syncthreads();
    }
    unsigned blkbase = lsum[0] + lsum[1] + lsum[2] + lsum[3];
    unsigned run = blkbase + ((t == 0) ? 0u : ps[t - 1]);
    unsigned o0 = run, o1 = o0 + v0, o2 = o1 + v1, o3 = o2 + v2;
    if (base + 3 < NN) {
        *reinterpret_cast<uint4*>(offs + base) = make_uint4(o0, o1, o2, o3);
        *reinterpret_cast<uint4*>(curs + base) = make_uint4(o0, o1, o2, o3);
    } else {
        if (base     < NN) { offs[base]     = o0; curs[base]     = o0; }
        if (base + 1 < NN) { offs[base + 1] = o1; curs[base + 1] = o1; }
        if (base + 2 < NN) { offs[base + 2] = o2; curs[base + 2] = o2; }
    }
    if (bid == NBLK - 1 && t == 255) offs[NN] = blkbase + ps[255];
}

// ---------------------------------------------------------------------------
// 3) Bin edges by target.
// ---------------------------------------------------------------------------
__global__ __launch_bounds__(256) void bin_k(
    const int* __restrict__ ei,
    unsigned* __restrict__ curs,
    int* __restrict__ esrc)
{
    int e = blockIdx.x * 256 + threadIdx.x;
    if (e >= NE) return;
    int s = ei[e];
    int t = ei[NE + e];
    if ((unsigned)s >= NN || (unsigned)t >= NN) return;
    unsigned pos = atomicAdd(&curs[t], 1u);
    esrc[pos] = s;
}

// ---------------------------------------------------------------------------
// 4) Fused mean + linear + residual, EDGE-PARALLEL gather:
//    Edges of the block's 32-node segment are distributed flat across the
//    block (8 lanes x 32B per edge); the target row is found by 5-step
//    binary search in the LDS offs window; accumulation is LDS atomicAdd
//    (ds_add_f32, no return -> loads pipeline). Removes the per-node
//    serial-loop degree imbalance (wave ran at max-degree of 8 nodes).
// ---------------------------------------------------------------------------
__global__ __launch_bounds__(256) void fused_bf16_k(
    const float* __restrict__ x,
    const ushortT* __restrict__ xb,
    const float* __restrict__ W,
    const float* __restrict__ b,
    const unsigned* __restrict__ offs,
    const int* __restrict__ esrc,
    float* __restrict__ out)
{
    __shared__ float Ws[WCH][DIM + PAD];
    __shared__ float mean_s[NPT][DIM + PAD];
    __shared__ unsigned soffs[33];

    const int t    = threadIdx.x;
    const int base = blockIdx.x * NPT;
    const int sn   = t >> 3;          // node slot 0..31
    const int so   = (t & 7) * 16;    // 16-float column chunk

    // zero accumulation region + stage offs window
    #pragma unroll
    for (int q = 0; q < 16; q += 4)
        *reinterpret_cast<float4*>(&mean_s[sn][so + q]) = make_float4(0.f, 0.f, 0.f, 0.f);
    if (t < 33) soffs[t] = offs[base + t];
    __syncthreads();

    // edge-parallel gather
    {
        const unsigned ebeg = soffs[0];
        const int nE = (int)(soffs[32] - ebeg);
        const int p16 = (t & 7) * 16;     // bf16 column offset (== so)
        for (int k = (t >> 3); k < nE; k += 32) {
            unsigned g = ebeg + (unsigned)k;
            int s = esrc[g];
            const ushort8* r = reinterpret_cast<const ushort8*>(xb + (size_t)s * DIM + p16);
            ushort8 u0 = r[0], u1 = r[1];
            // binary search: node i with soffs[i] <= g < soffs[i+1]
            int lo = 0, hi = 32;
            #pragma unroll
            for (int it = 0; it < 5; ++it) {
                int mid = (lo + hi) >> 1;
                bool c = (g >= soffs[mid]);
                lo = c ? mid : lo;
                hi = c ? hi : mid;
            }
            float* mrow = &mean_s[lo][p16];
            #pragma unroll
            for (int q = 0; q < 8; ++q) {
                atomicAdd(&mrow[q],     b2f(u0[q]));
                atomicAdd(&mrow[q + 8], b2f(u1[q]));
            }
        }
    }
    __syncthreads();

    // divide by count
    {
        float inv = 1.0f / fmaxf((float)(soffs[sn + 1] - soffs[sn]), 1.0f);
        #pragma unroll
        for (int q = 0; q < 16; ++q) mean_s[sn][so + q] *= inv;
    }

    const int og = (t & 31) * 4;
    const int ng = (t >> 5) * 4;

    float4 acc[4];
    #pragma unroll
    for (int n = 0; n < 4; ++n) acc[n] = make_float4(0.f, 0.f, 0.f, 0.f);

    for (int c = 0; c < DIM / WCH; ++c) {
        __syncthreads();   // (c=0: also covers the divide)
        #pragma unroll
        for (int k = 0; k < (DIM * WCH) / 256; ++k) {
            int idx = t + k * 256;
            int o   = idx >> 4;
            int il  = idx & 15;
            Ws[il][o] = W[o * DIM + c * WCH + il];
        }
        __syncthreads();

        #pragma unroll
        for (int i = 0; i < WCH; i += 4) {
            float4 m4[4];
            #pragma unroll
            for (int n = 0; n < 4; ++n)
                m4[n] = *reinterpret_cast<const float4*>(&mean_s[ng + n][c * WCH + i]);
            #pragma unroll
            for (int j = 0; j < 4; ++j) {
                float4 w = *reinterpret_cast<const float4*>(&Ws[i + j][og]);
                #pragma unroll
                for (int n = 0; n < 4; ++n) {
                    float m = (j == 0) ? m4[n].x : (j == 1) ? m4[n].y
                            : (j == 2) ? m4[n].z : m4[n].w;
                    acc[n].x += m * w.x;
                    acc[n].y += m * w.y;
                    acc[n].z += m * w.z;
                    acc[n].w += m * w.w;
                }
            }
        }
    }

    float4 bv = *reinterpret_cast<const float4*>(b + og);
    #pragma unroll
    for (int n = 0; n < 4; ++n) {
        int node = base + ng + n;
        float4 xv = *reinterpret_cast<const float4*>(x + (size_t)node * DIM + og);
        float4 o4;
        o4.x = xv.x + bv.x + acc[n].x;
        o4.y = xv.y + bv.y + acc[n].y;
        o4.z = xv.z + bv.z + acc[n].z;
        o4.w = xv.w + bv.w + acc[n].w;
        *reinterpret_cast<float4*>(out + (size_t)node * DIM + og) = o4;
    }
}

extern "C" void kernel_launch(void* const* d_in, const int* in_sizes, int n_in,
                              void* d_out, int out_size, void* d_ws, size_t ws_size,
                              hipStream_t stream) {
    const float* x  = (const float*)d_in[0];
    const int*   ei = (const int*)d_in[1];     // int32 per harness contract
    const float* W  = (const float*)d_in[2];
    const float* b  = (const float*)d_in[3];
    float* out = (float*)d_out;

    unsigned* cnts   = (unsigned*)d_ws;
    unsigned* offs   = cnts + NN;
    unsigned* curs   = cnts + 2 * NN + 4;
    int*      esrc   = (int*)(cnts + 3 * NN + 4);
    unsigned* blksum = (unsigned*)(esrc + NE);          // 128
    ushortT*  xb     = (ushortT*)(blksum + 128);        // NN*DIM bf16

    hipMemsetAsync(cnts, 0, (size_t)NN * sizeof(unsigned), stream);

    prep_k  <<<CASTB + HISTB, 256, 0, stream>>>(x, xb, ei, cnts);
    scan_a_k<<<NBLK, 256, 0, stream>>>(cnts, blksum);
    scan_c_k<<<NBLK, 256, 0, stream>>>(cnts, blksum, offs, curs);
    bin_k   <<<(NE + 255) / 256, 256, 0, stream>>>(ei, curs, esrc);

    fused_bf16_k<<<NN / NPT, 256, 0, stream>>>(x, xb, W, b, offs, esrc, out);
}

// Round 14
// 148.237 us; speedup vs baseline: 3.8582x; 3.8582x over previous
//
#include <hip/hip_runtime.h>

#define NN    100000
#define NE    640000
#define DIM   128
#define NPT   32    // nodes per fused tile (= M of the MFMA tile)
#define TILE  1024  // scan tile (elements per block)
#define NBLK  98    // ceil(NN / TILE)
#define CASTB 6250  // NN*DIM/8/256 (exact)
#define HISTB 2500  // NE/256 (exact)
#define WCASTB 8    // 128*128/8/256 (exact)

typedef unsigned short ushortT;
typedef ushortT ushort8 __attribute__((ext_vector_type(8)));
typedef short   short8v __attribute__((ext_vector_type(8)));   // MFMA A/B frag (8 bf16)
typedef float   float4v __attribute__((ext_vector_type(4)));   // MFMA C/D frag

__device__ __forceinline__ ushortT f2b(float f) {      // fp32 -> bf16 RNE
    unsigned b = __float_as_uint(f);
    return (ushortT)((b + 0x7FFFu + ((b >> 16) & 1u)) >> 16);
}
__device__ __forceinline__ float b2f(ushortT u) {      // bf16 -> fp32 exact
    return __uint_as_float(((unsigned)u) << 16);
}

// ws layout (4-byte units):
//   cnts [0, NN)  offs [NN, 2NN+4)  curs [2NN+4, 3NN+4)
//   esrc [3NN+4, +NE)  blksum [+128]
//   xb  (bf16, NN*DIM)   Wb (bf16, DIM*DIM)    total ~29.4 MB

// ---------------------------------------------------------------------------
// 0) prep: cast x->bf16 [0,CASTB) | hist [CASTB,+HISTB) | cast W->bf16 (+8).
//    cnts zeroed beforehand by hipMemsetAsync.
// ---------------------------------------------------------------------------
__global__ __launch_bounds__(256) void prep_k(
    const float* __restrict__ x, ushortT* __restrict__ xb,
    const float* __restrict__ W, ushortT* __restrict__ Wb,
    const int* __restrict__ ei, unsigned* __restrict__ cnts)
{
    int bid = blockIdx.x;
    if (bid < CASTB) {
        int i = (bid * 256 + threadIdx.x) * 8;
        float4 f0 = *reinterpret_cast<const float4*>(x + i);
        float4 f1 = *reinterpret_cast<const float4*>(x + i + 4);
        ushort8 u;
        u[0] = f2b(f0.x); u[1] = f2b(f0.y); u[2] = f2b(f0.z); u[3] = f2b(f0.w);
        u[4] = f2b(f1.x); u[5] = f2b(f1.y); u[6] = f2b(f1.z); u[7] = f2b(f1.w);
        *reinterpret_cast<ushort8*>(xb + i) = u;
    } else if (bid < CASTB + HISTB) {
        int e = (bid - CASTB) * 256 + threadIdx.x;
        int t = ei[NE + e];
        if ((unsigned)t < NN) atomicAdd(&cnts[t], 1u);
    } else {
        int i = ((bid - CASTB - HISTB) * 256 + threadIdx.x) * 8;
        float4 f0 = *reinterpret_cast<const float4*>(W + i);
        float4 f1 = *reinterpret_cast<const float4*>(W + i + 4);
        ushort8 u;
        u[0] = f2b(f0.x); u[1] = f2b(f0.y); u[2] = f2b(f0.z); u[3] = f2b(f0.w);
        u[4] = f2b(f1.x); u[5] = f2b(f1.y); u[6] = f2b(f1.z); u[7] = f2b(f1.w);
        *reinterpret_cast<ushort8*>(Wb + i) = u;
    }
}

// ---------------------------------------------------------------------------
// 2a) Per-block sums of 1024-elem tiles.
// ---------------------------------------------------------------------------
__global__ __launch_bounds__(256) void scan_a_k(
    const unsigned* __restrict__ cnts, unsigned* __restrict__ blksum)
{
    __shared__ unsigned red[4];
    int t    = threadIdx.x;
    int base = blockIdx.x * TILE + t * 4;
    unsigned v = 0;
    if (base + 3 < NN) {
        uint4 u = *reinterpret_cast<const uint4*>(cnts + base);
        v = u.x + u.y + u.z + u.w;
    } else {
        for (int k = 0; k < 4; ++k) if (base + k < NN) v += cnts[base + k];
    }
    #pragma unroll
    for (int off = 32; off; off >>= 1) v += __shfl_down(v, off);
    if ((t & 63) == 0) red[t >> 6] = v;
    __syncthreads();
    if (t == 0) blksum[blockIdx.x] = red[0] + red[1] + red[2] + red[3];
}

// ---------------------------------------------------------------------------
// 2b) Per-block scan (+ inline base from blksum) -> offs, curs.
// ---------------------------------------------------------------------------
__global__ __launch_bounds__(256) void scan_c_k(
    const unsigned* __restrict__ cnts,
    const unsigned* __restrict__ blksum,
    unsigned* __restrict__ offs,
    unsigned* __restrict__ curs)
{
    __shared__ unsigned ps[256];
    __shared__ unsigned lsum[4];
    int t    = threadIdx.x;
    int bid  = blockIdx.x;
    int base = bid * TILE + t * 4;

    unsigned part = 0;
    for (int j = t; j < bid; j += 256) part += blksum[j];
    #pragma unroll
    for (int off = 32; off; off >>= 1) part += __shfl_down(part, off);
    if ((t & 63) == 0) lsum[t >> 6] = part;

    unsigned v0 = 0, v1 = 0, v2 = 0, v3 = 0;
    if (base + 3 < NN) {
        uint4 u = *reinterpret_cast<const uint4*>(cnts + base);
        v0 = u.x; v1 = u.y; v2 = u.z; v3 = u.w;
    } else {
        if (base     < NN) v0 = cnts[base];
        if (base + 1 < NN) v1 = cnts[base + 1];
        if (base + 2 < NN) v2 = cnts[base + 2];
    }
    ps[t] = v0 + v1 + v2 + v3;
    __syncthreads();
    for (int off = 1; off < 256; off <<= 1) {
        unsigned u = (t >= off) ? ps[t - off] : 0u;
        __syncthreads();
        ps[t] += u;
        __syncthreads();
    }
    unsigned blkbase = lsum[0] + lsum[1] + lsum[2] + lsum[3];
    unsigned run = blkbase + ((t == 0) ? 0u : ps[t - 1]);
    unsigned o0 = run, o1 = o0 + v0, o2 = o1 + v1, o3 = o2 + v2;
    if (base + 3 < NN) {
        *reinterpret_cast<uint4*>(offs + base) = make_uint4(o0, o1, o2, o3);
        *reinterpret_cast<uint4*>(curs + base) = make_uint4(o0, o1, o2, o3);
    } else {
        if (base     < NN) { offs[base]     = o0; curs[base]     = o0; }
        if (base + 1 < NN) { offs[base + 1] = o1; curs[base + 1] = o1; }
        if (base + 2 < NN) { offs[base + 2] = o2; curs[base + 2] = o2; }
    }
    if (bid == NBLK - 1 && t == 255) offs[NN] = blkbase + ps[255];
}

// ---------------------------------------------------------------------------
// 3) Bin edges by target.
// ---------------------------------------------------------------------------
__global__ __launch_bounds__(256) void bin_k(
    const int* __restrict__ ei,
    unsigned* __restrict__ curs,
    int* __restrict__ esrc)
{
    int e = blockIdx.x * 256 + threadIdx.x;
    if (e >= NE) return;
    int s = ei[e];
    int t = ei[NE + e];
    if ((unsigned)s >= NN || (unsigned)t >= NN) return;
    unsigned pos = atomicAdd(&curs[t], 1u);
    esrc[pos] = s;
}

// ---------------------------------------------------------------------------
// 4) Fused mean(bf16 gather, r11 structure) + MFMA bf16 GEMM + residual.
//    Gather: 8 threads/node, 2-edge unroll, fp32 accum -> bf16 LDS.
//    GEMM: 32x128x128 via mfma_f32_16x16x32_bf16; A from LDS (mean rows),
//    B straight from global Wb rows (L2-hot). fp32 epilogue w/ x + b.
//    LDS: mean_s[32][136] bf16 = 8.7 KB (272B row stride: 16B-aligned,
//    2-way-max bank aliasing on b128 frag reads = free).
// ---------------------------------------------------------------------------
__global__ __launch_bounds__(256) void fused_k(
    const float* __restrict__ x,
    const ushortT* __restrict__ xb,
    const ushortT* __restrict__ Wb,
    const float* __restrict__ b,
    const unsigned* __restrict__ offs,
    const int* __restrict__ esrc,
    float* __restrict__ out)
{
    __shared__ short mean_s[NPT][136];

    const int t    = threadIdx.x;
    const int base = blockIdx.x * NPT;

    // ---- gather phase (r11-identical accumulation) ----
    {
        int sn   = t >> 3;
        int so   = (t & 7) * 16;
        int node = base + sn;
        unsigned beg = offs[node], end = offs[node + 1];
        float aa[16], cc[16];
        #pragma unroll
        for (int k = 0; k < 16; ++k) { aa[k] = 0.f; cc[k] = 0.f; }

        unsigned j = beg;
        int s0 = 0, s1 = 0;
        if (j + 1 < end) { s0 = esrc[j]; s1 = esrc[j + 1]; }
        while (j + 1 < end) {
            unsigned jn = j + 2;
            int t0 = 0, t1 = 0;
            if (jn + 1 < end) { t0 = esrc[jn]; t1 = esrc[jn + 1]; }
            const ushort8* r0 = reinterpret_cast<const ushort8*>(xb + (size_t)s0 * DIM + so);
            const ushort8* r1 = reinterpret_cast<const ushort8*>(xb + (size_t)s1 * DIM + so);
            ushort8 p0 = r0[0], p1 = r0[1];
            ushort8 q0 = r1[0], q1 = r1[1];
            #pragma unroll
            for (int k = 0; k < 8; ++k) {
                aa[k]     += b2f(p0[k]);
                aa[k + 8] += b2f(p1[k]);
                cc[k]     += b2f(q0[k]);
                cc[k + 8] += b2f(q1[k]);
            }
            s0 = t0; s1 = t1;
            j = jn;
        }
        if (j < end) {   // odd tail edge
            int s = esrc[j];
            const ushort8* r0 = reinterpret_cast<const ushort8*>(xb + (size_t)s * DIM + so);
            ushort8 p0 = r0[0], p1 = r0[1];
            #pragma unroll
            for (int k = 0; k < 8; ++k) {
                aa[k]     += b2f(p0[k]);
                aa[k + 8] += b2f(p1[k]);
            }
        }
        float inv = 1.0f / fmaxf((float)(end - beg), 1.0f);
        short8v lo, hi;
        #pragma unroll
        for (int k = 0; k < 8; ++k) {
            lo[k] = (short)f2b((aa[k]     + cc[k])     * inv);
            hi[k] = (short)f2b((aa[k + 8] + cc[k + 8]) * inv);
        }
        *reinterpret_cast<short8v*>(&mean_s[sn][so])     = lo;
        *reinterpret_cast<short8v*>(&mean_s[sn][so + 8]) = hi;
    }
    __syncthreads();

    // ---- MFMA GEMM phase ----
    const int wid  = t >> 6;        // wave 0..3 -> output col-block pair
    const int lane = t & 63;
    const int lrow = lane & 15;     // m (A) / n (B) index within fragment
    const int lko  = (lane >> 4) * 8;   // k-octet base within K=32 slice

    // A fragments: 2 row-halves x 4 K-slices
    short8v afr[2][4];
    #pragma unroll
    for (int mi = 0; mi < 2; ++mi)
        #pragma unroll
        for (int kq = 0; kq < 4; ++kq)
            afr[mi][kq] = *reinterpret_cast<const short8v*>(
                &mean_s[mi * 16 + lrow][kq * 32 + lko]);

    float4v acc[2][2];
    #pragma unroll
    for (int mi = 0; mi < 2; ++mi)
        #pragma unroll
        for (int ni = 0; ni < 2; ++ni)
            acc[mi][ni] = (float4v){0.f, 0.f, 0.f, 0.f};

    #pragma unroll
    for (int ni = 0; ni < 2; ++ni) {
        int o = (wid * 2 + ni) * 16 + lrow;          // output column (W row)
        #pragma unroll
        for (int kq = 0; kq < 4; ++kq) {
            short8v bfr = *reinterpret_cast<const short8v*>(
                Wb + (size_t)o * DIM + kq * 32 + lko);
            acc[0][ni] = __builtin_amdgcn_mfma_f32_16x16x32_bf16(
                afr[0][kq], bfr, acc[0][ni], 0, 0, 0);
            acc[1][ni] = __builtin_amdgcn_mfma_f32_16x16x32_bf16(
                afr[1][kq], bfr, acc[1][ni], 0, 0, 0);
        }
    }

    // ---- epilogue: out = x + b + acc  (C layout: col=lane&15, row=(lane>>4)*4+r)
    #pragma unroll
    for (int ni = 0; ni < 2; ++ni) {
        int o = (wid * 2 + ni) * 16 + lrow;
        float bv = b[o];
        #pragma unroll
        for (int mi = 0; mi < 2; ++mi) {
            #pragma unroll
            for (int r = 0; r < 4; ++r) {
                int node = base + mi * 16 + (lane >> 4) * 4 + r;
                size_t idx = (size_t)node * DIM + o;
                out[idx] = x[idx] + bv + acc[mi][ni][r];
            }
        }
    }
}

extern "C" void kernel_launch(void* const* d_in, const int* in_sizes, int n_in,
                              void* d_out, int out_size, void* d_ws, size_t ws_size,
                              hipStream_t stream) {
    const float* x  = (const float*)d_in[0];
    const int*   ei = (const int*)d_in[1];     // int32 per harness contract
    const float* W  = (const float*)d_in[2];
    const float* b  = (const float*)d_in[3];
    float* out = (float*)d_out;

    unsigned* cnts   = (unsigned*)d_ws;
    unsigned* offs   = cnts + NN;
    unsigned* curs   = cnts + 2 * NN + 4;
    int*      esrc   = (int*)(cnts + 3 * NN + 4);
    unsigned* blksum = (unsigned*)(esrc + NE);          // 128
    ushortT*  xb     = (ushortT*)(blksum + 128);        // NN*DIM bf16
    ushortT*  Wb     = xb + (size_t)NN * DIM;           // DIM*DIM bf16

    hipMemsetAsync(cnts, 0, (size_t)NN * sizeof(unsigned), stream);

    prep_k  <<<CASTB + HISTB + WCASTB, 256, 0, stream>>>(x, xb, W, Wb, ei, cnts);
    scan_a_k<<<NBLK, 256, 0, stream>>>(cnts, blksum);
    scan_c_k<<<NBLK, 256, 0, stream>>>(cnts, blksum, offs, curs);
    bin_k   <<<(NE + 255) / 256, 256, 0, stream>>>(ei, curs, esrc);

    fused_k <<<NN / NPT, 256, 0, stream>>>(x, xb, Wb, b, offs, esrc, out);
}